// Round 8
// baseline (479.889 us; speedup 1.0000x reference)
//
#include <hip/hip_runtime.h>

// GraphConstruction: x[1,1024,1024] fp32 -> A[4096,4096] in {0,1} fp32.
// patches[n,r,k] = x[h,w], h = (n&15)*64 + (r>>2)*16 + (n>>8),
//                          w = (r&3)*256 + k*16 + ((n>>4)&15)
// LOCKED NUMERICS (R6/R7, absmax 0):
//   sq[n,k]: acc = p0^2; acc = acc + fl(p_r^2), r ascending (plain adds)
//   G: acc = fmaf(a_r, b_r, acc), r ascending;  d2 = fmaf(-2,G,fl(si+sj))
//   decision: all_k (d2 <= 49.0f);  A bit-exactly symmetric -> mirror stores.
// R8: 8x8 cells/thread (1 B LDS-read per fma, was 2), 64-thread (1-wave)
//     blocks keep grid at 2080 (good packing; barriers ~free), float4 global
//     staging (one load = 4 tile rows at fixed (r,k)), bad-bitmask instead of
//     m[] (saves 62 VGPRs). KC=2 -> 17.4 KB LDS -> 9 blocks/CU.

#define NPATCH 4096
#define BT 64
#define KC 2
#define NPH 8

__global__ __launch_bounds__(64, 3) void adj_kernel(const float* __restrict__ x,
                                                    float* __restrict__ A) {
#pragma clang fp contract(off)
    // Row = 8 float4 chunks (kl*4+rc)^((row>>2)&7), elem = r&3.
    // Reads: a-side 8 addrs -> 4 quads 2-way; b-side 16 addrs -> 8 quads
    // 2-way; writes 2-way. All free (m136).
    __shared__ float4 Si[BT][8];
    __shared__ float4 Sj[BT][8];
    __shared__ float sqs[2][KC][BT];

    // linear -> lower-triangle (bi >= bj)
    int t = blockIdx.x;
    int bi = (int)((sqrtf(8.0f * (float)t + 1.0f) - 1.0f) * 0.5f);
    while ((bi + 1) * (bi + 2) / 2 <= t) ++bi;
    while (bi * (bi + 1) / 2 > t) --bi;
    int bj = t - bi * (bi + 1) / 2;

    const int i0 = bi * BT;
    const int j0 = bj * BT;
    const int tid = threadIdx.x;
    const int tx = tid & 7;        // j-group: cols tx*8..tx*8+7
    const int ty = tid >> 3;       // i-group: rows ty*8..ty*8+7

    unsigned int bad_lo = 0u, bad_hi = 0u;   // bit u*8+v set => some d2 > 49

    for (int kp = 0; kp < NPH; ++kp) {
        __syncthreads();
        // ---- stage: float4 global loads; one load covers rows {16d+rl} ----
#pragma unroll 4
        for (int p = 0; p < 16; ++p) {
            int gid = p * 64 + tid;            // 1024 loads/phase
            int side = gid >> 9;
            int q = gid & 511;
            int kl = q & 1;
            int r = (q >> 1) & 15;
            int rl = q >> 5;                   // 0..15
            int k = kp * KC + kl;
            int b = side ? bj : bi;
            int h = rl * 64 + (r >> 2) * 16 + (b >> 2);
            int w0 = (r & 3) * 256 + k * 16 + ((4 * b) & 15);
            float4 v = *(const float4*)&x[h * 1024 + w0];
            const float* vp = (const float*)&v;
            int c = (kl << 2) | (r >> 2);
            int e = r & 3;
            float4* Sb = side ? &Sj[0][0] : &Si[0][0];
#pragma unroll
            for (int dd = 0; dd < 4; ++dd) {   // elem dd -> row 16*dd+rl
                int row = 16 * dd + rl;
                int ch = c ^ ((row >> 2) & 7);
                ((float*)&Sb[row * 8 + ch])[e] = vp[dd];
            }
        }
        __syncthreads();
        // ---- per-column sq: plain adds, r ascending ----
#pragma unroll
        for (int p = 0; p < 4; ++p) {
            int s0 = p * 64 + tid;             // 256 values/phase
            int side = s0 >> 7;
            int kl = (s0 >> 6) & 1;
            int row = s0 & 63;
            const float4* Sb = side ? &Sj[row][0] : &Si[row][0];
            int swz = (row >> 2) & 7;
            float acc;
            {
                float4 v = Sb[(kl * 4) ^ swz];
                acc = v.x * v.x;
                float t1 = v.y * v.y; acc = acc + t1;
                float t2 = v.z * v.z; acc = acc + t2;
                float t3 = v.w * v.w; acc = acc + t3;
            }
#pragma unroll
            for (int rc = 1; rc < 4; ++rc) {
                float4 v = Sb[(kl * 4 + rc) ^ swz];
                float t0 = v.x * v.x; acc = acc + t0;
                float t1 = v.y * v.y; acc = acc + t1;
                float t2 = v.z * v.z; acc = acc + t2;
                float t3 = v.w * v.w; acc = acc + t3;
            }
            sqs[side][kl][row] = acc;
        }
        __syncthreads();
        // ---- compute: 8x8 cells, fmaf chains r ascending ----
#pragma unroll
        for (int kl = 0; kl < KC; ++kl) {
            float d[8][8];
#pragma unroll
            for (int u = 0; u < 8; ++u)
#pragma unroll
                for (int v = 0; v < 8; ++v) d[u][v] = 0.0f;
#pragma unroll
            for (int rc = 0; rc < 4; ++rc) {
                int c = kl * 4 + rc;
                float4 a[8], b[8];
#pragma unroll
                for (int u = 0; u < 8; ++u)
                    a[u] = Si[ty * 8 + u][c ^ ((2 * ty + (u >> 2)) & 7)];
#pragma unroll
                for (int v = 0; v < 8; ++v)
                    b[v] = Sj[tx * 8 + v][c ^ ((2 * tx + (v >> 2)) & 7)];
#pragma unroll
                for (int u = 0; u < 8; ++u)
#pragma unroll
                    for (int v = 0; v < 8; ++v) {
                        d[u][v] = fmaf(a[u].x, b[v].x, d[u][v]);
                        d[u][v] = fmaf(a[u].y, b[v].y, d[u][v]);
                        d[u][v] = fmaf(a[u].z, b[v].z, d[u][v]);
                        d[u][v] = fmaf(a[u].w, b[v].w, d[u][v]);
                    }
            }
            float4 siA = *(const float4*)&sqs[0][kl][ty * 8];
            float4 siB = *(const float4*)&sqs[0][kl][ty * 8 + 4];
            float4 sjA = *(const float4*)&sqs[1][kl][tx * 8];
            float4 sjB = *(const float4*)&sqs[1][kl][tx * 8 + 4];
            const float* sip = (const float*)&siA;   // siA,siB contiguous? no:
            float si[8], sj[8];
            si[0]=siA.x; si[1]=siA.y; si[2]=siA.z; si[3]=siA.w;
            si[4]=siB.x; si[5]=siB.y; si[6]=siB.z; si[7]=siB.w;
            sj[0]=sjA.x; sj[1]=sjA.y; sj[2]=sjA.z; sj[3]=sjA.w;
            sj[4]=sjB.x; sj[5]=sjB.y; sj[6]=sjB.z; sj[7]=sjB.w;
            (void)sip;
#pragma unroll
            for (int u = 0; u < 8; ++u)
#pragma unroll
                for (int v = 0; v < 8; ++v) {
                    float s = si[u] + sj[v];              // fl(si+sj)
                    float d2 = fmaf(-2.0f, d[u][v], s);   // fl(s-2G)
                    int idx = u * 8 + v;
                    if (idx < 32) bad_lo |= (d2 > 49.0f) ? (1u << idx) : 0u;
                    else          bad_hi |= (d2 > 49.0f) ? (1u << (idx - 32)) : 0u;
                }
        }
    }

    // ---- stores: direct + mirrored (A exactly symmetric) ----
#pragma unroll
    for (int u = 0; u < 8; ++u) {
#pragma unroll
        for (int g = 0; g < 2; ++g) {
            float o[4];
#pragma unroll
            for (int e = 0; e < 4; ++e) {
                int idx = u * 8 + g * 4 + e;
                unsigned int bit = (idx < 32) ? (bad_lo >> idx) : (bad_hi >> (idx - 32));
                o[e] = (bit & 1u) ? 0.0f : 1.0f;
            }
            *(float4*)&A[(size_t)(i0 + ty * 8 + u) * NPATCH + j0 + tx * 8 + g * 4] =
                make_float4(o[0], o[1], o[2], o[3]);
        }
    }
    if (bi != bj) {
#pragma unroll
        for (int v = 0; v < 8; ++v) {
#pragma unroll
            for (int g = 0; g < 2; ++g) {
                float o[4];
#pragma unroll
                for (int e = 0; e < 4; ++e) {
                    int idx = (g * 4 + e) * 8 + v;
                    unsigned int bit = (idx < 32) ? (bad_lo >> idx) : (bad_hi >> (idx - 32));
                    o[e] = (bit & 1u) ? 0.0f : 1.0f;
                }
                *(float4*)&A[(size_t)(j0 + tx * 8 + v) * NPATCH + i0 + ty * 8 + g * 4] =
                    make_float4(o[0], o[1], o[2], o[3]);
            }
        }
    }
}

extern "C" void kernel_launch(void* const* d_in, const int* in_sizes, int n_in,
                              void* d_out, int out_size, void* d_ws, size_t ws_size,
                              hipStream_t stream) {
    const float* x = (const float*)d_in[0];
    float* A = (float*)d_out;
    (void)d_ws; (void)ws_size;

    const int nblk = (NPATCH / BT) * (NPATCH / BT + 1) / 2;  // 2080
    adj_kernel<<<nblk, 64, 0, stream>>>(x, A);
}

// Round 9
// 281.669 us; speedup vs baseline: 1.7037x; 1.7037x over previous
//
#include <hip/hip_runtime.h>

// GraphConstruction: x[1,1024,1024] fp32 -> A[4096,4096] in {0,1} fp32.
// patches[n,r,k] = x[h,w], h = (n&15)*64 + (r>>2)*16 + (n>>8),
//                          w = (r&3)*256 + k*16 + ((n>>4)&15)
// LOCKED NUMERICS (R6/R7, absmax 0):
//   sq[n,k]: acc = p0^2; acc = acc + fl(p_r^2), r ascending (plain adds)
//   G: acc = fmaf(a_r, b_r, acc), r ascending;  d2 = fmaf(-2,G,fl(si+sj))
//   decision: all_k (d2 <= 49.0f);  A bit-exactly symmetric -> mirror stores.
// R9: R8 structure, spill fix. R8 failed on register spills
//     (launch_bounds(64,3) -> 170-reg cap vs ~150+ live set -> compiler
//     spilled d[8][8]; VGPR_Count 84, 1.6 GB scratch HBM traffic).
//     launch_bounds(64,2) -> 256-reg cap. 17.4 KB LDS -> 8-9 blocks/CU.

#define NPATCH 4096
#define BT 64
#define KC 2
#define NPH 8

__global__ __launch_bounds__(64, 2) void adj_kernel(const float* __restrict__ x,
                                                    float* __restrict__ A) {
#pragma clang fp contract(off)
    // Row = 8 float4 chunks, chunk (kl*4+rc)^((row>>2)&7), elem = r&3.
    // All LDS reads/writes <=2-way per bank-quad (free, m136).
    __shared__ float4 Si[BT][8];
    __shared__ float4 Sj[BT][8];
    __shared__ float sqs[2][KC][BT];

    // linear -> lower-triangle (bi >= bj)
    int t = blockIdx.x;
    int bi = (int)((sqrtf(8.0f * (float)t + 1.0f) - 1.0f) * 0.5f);
    while ((bi + 1) * (bi + 2) / 2 <= t) ++bi;
    while (bi * (bi + 1) / 2 > t) --bi;
    int bj = t - bi * (bi + 1) / 2;

    const int i0 = bi * BT;
    const int j0 = bj * BT;
    const int tid = threadIdx.x;
    const int tx = tid & 7;        // j-group: cols tx*8..tx*8+7
    const int ty = tid >> 3;       // i-group: rows ty*8..ty*8+7

    unsigned int bad_lo = 0u, bad_hi = 0u;   // bit u*8+v set => some d2 > 49

    for (int kp = 0; kp < NPH; ++kp) {
        __syncthreads();
        // ---- stage: float4 global loads; one load covers rows {16*dd+rl} ----
#pragma unroll 4
        for (int p = 0; p < 16; ++p) {
            int gid = p * 64 + tid;            // 1024 loads/phase
            int side = gid >> 9;
            int q = gid & 511;
            int kl = q & 1;
            int r = (q >> 1) & 15;
            int rl = q >> 5;                   // 0..15
            int k = kp * KC + kl;
            int b = side ? bj : bi;
            int h = rl * 64 + (r >> 2) * 16 + (b >> 2);
            int w0 = (r & 3) * 256 + k * 16 + ((4 * b) & 15);
            float4 v = *(const float4*)&x[h * 1024 + w0];
            const float* vp = (const float*)&v;
            int c = (kl << 2) | (r >> 2);
            int e = r & 3;
            float4* Sb = side ? &Sj[0][0] : &Si[0][0];
#pragma unroll
            for (int dd = 0; dd < 4; ++dd) {   // elem dd -> row 16*dd+rl
                int row = 16 * dd + rl;
                int ch = c ^ ((row >> 2) & 7);
                ((float*)&Sb[row * 8 + ch])[e] = vp[dd];
            }
        }
        __syncthreads();
        // ---- per-column sq: plain adds, r ascending ----
#pragma unroll
        for (int p = 0; p < 4; ++p) {
            int s0 = p * 64 + tid;             // 256 values/phase
            int side = s0 >> 7;
            int kl = (s0 >> 6) & 1;
            int row = s0 & 63;
            const float4* Sb = side ? &Sj[row][0] : &Si[row][0];
            int swz = (row >> 2) & 7;
            float acc;
            {
                float4 v = Sb[(kl * 4) ^ swz];
                acc = v.x * v.x;
                float t1 = v.y * v.y; acc = acc + t1;
                float t2 = v.z * v.z; acc = acc + t2;
                float t3 = v.w * v.w; acc = acc + t3;
            }
#pragma unroll
            for (int rc = 1; rc < 4; ++rc) {
                float4 v = Sb[(kl * 4 + rc) ^ swz];
                float t0 = v.x * v.x; acc = acc + t0;
                float t1 = v.y * v.y; acc = acc + t1;
                float t2 = v.z * v.z; acc = acc + t2;
                float t3 = v.w * v.w; acc = acc + t3;
            }
            sqs[side][kl][row] = acc;
        }
        __syncthreads();
        // ---- compute: 8x8 cells, fmaf chains r ascending ----
#pragma unroll
        for (int kl = 0; kl < KC; ++kl) {
            float d[8][8];
#pragma unroll
            for (int u = 0; u < 8; ++u)
#pragma unroll
                for (int v = 0; v < 8; ++v) d[u][v] = 0.0f;
#pragma unroll
            for (int rc = 0; rc < 4; ++rc) {
                int c = kl * 4 + rc;
                float4 a[8], b[8];
#pragma unroll
                for (int u = 0; u < 8; ++u)
                    a[u] = Si[ty * 8 + u][c ^ ((2 * ty + (u >> 2)) & 7)];
#pragma unroll
                for (int v = 0; v < 8; ++v)
                    b[v] = Sj[tx * 8 + v][c ^ ((2 * tx + (v >> 2)) & 7)];
#pragma unroll
                for (int u = 0; u < 8; ++u)
#pragma unroll
                    for (int v = 0; v < 8; ++v) {
                        d[u][v] = fmaf(a[u].x, b[v].x, d[u][v]);
                        d[u][v] = fmaf(a[u].y, b[v].y, d[u][v]);
                        d[u][v] = fmaf(a[u].z, b[v].z, d[u][v]);
                        d[u][v] = fmaf(a[u].w, b[v].w, d[u][v]);
                    }
            }
#pragma unroll
            for (int u = 0; u < 8; ++u) {
                float si = ((const float*)&sqs[0][kl][0])[ty * 8 + u];
#pragma unroll
                for (int v = 0; v < 8; ++v) {
                    float sj = ((const float*)&sqs[1][kl][0])[tx * 8 + v];
                    float s = si + sj;                    // fl(si+sj)
                    float d2 = fmaf(-2.0f, d[u][v], s);   // fl(s-2G)
                    int idx = u * 8 + v;
                    if (idx < 32) bad_lo |= (d2 > 49.0f) ? (1u << idx) : 0u;
                    else          bad_hi |= (d2 > 49.0f) ? (1u << (idx - 32)) : 0u;
                }
            }
        }
    }

    // ---- stores: direct + mirrored (A exactly symmetric) ----
#pragma unroll
    for (int u = 0; u < 8; ++u) {
#pragma unroll
        for (int g = 0; g < 2; ++g) {
            float o[4];
#pragma unroll
            for (int e = 0; e < 4; ++e) {
                int idx = u * 8 + g * 4 + e;
                unsigned int bit = (idx < 32) ? (bad_lo >> idx) : (bad_hi >> (idx - 32));
                o[e] = (bit & 1u) ? 0.0f : 1.0f;
            }
            *(float4*)&A[(size_t)(i0 + ty * 8 + u) * NPATCH + j0 + tx * 8 + g * 4] =
                make_float4(o[0], o[1], o[2], o[3]);
        }
    }
    if (bi != bj) {
#pragma unroll
        for (int v = 0; v < 8; ++v) {
#pragma unroll
            for (int g = 0; g < 2; ++g) {
                float o[4];
#pragma unroll
                for (int e = 0; e < 4; ++e) {
                    int idx = (g * 4 + e) * 8 + v;
                    unsigned int bit = (idx < 32) ? (bad_lo >> idx) : (bad_hi >> (idx - 32));
                    o[e] = (bit & 1u) ? 0.0f : 1.0f;
                }
                *(float4*)&A[(size_t)(j0 + tx * 8 + v) * NPATCH + i0 + ty * 8 + g * 4] =
                    make_float4(o[0], o[1], o[2], o[3]);
            }
        }
    }
}

extern "C" void kernel_launch(void* const* d_in, const int* in_sizes, int n_in,
                              void* d_out, int out_size, void* d_ws, size_t ws_size,
                              hipStream_t stream) {
    const float* x = (const float*)d_in[0];
    float* A = (float*)d_out;
    (void)d_ws; (void)ws_size;

    const int nblk = (NPATCH / BT) * (NPATCH / BT + 1) / 2;  // 2080
    adj_kernel<<<nblk, 64, 0, stream>>>(x, A);
}

// Round 10
// 157.847 us; speedup vs baseline: 3.0402x; 1.7844x over previous
//
#include <hip/hip_runtime.h>

// GraphConstruction: x[1,1024,1024] fp32 -> A[4096,4096] in {0,1} fp32.
// patches[n,r,k] = x[h,w], h = (n&15)*64 + (r>>2)*16 + (n>>8),
//                          w = (r&3)*256 + k*16 + ((n>>4)&15)
// LOCKED NUMERICS (R6/R7/R9, absmax 0):
//   sq[n,k]: acc = p0^2; acc = acc + fl(p_r^2), r ascending (plain adds)
//   G: acc = fmaf(a_r, b_r, acc), r ascending;  d2 = fmaf(-2,G,fl(si+sj))
//   decision: all_k (d2 <= 49.0f);  A bit-exactly symmetric -> mirror stores.
// R10: R7's spill-free 4x4/256-thread compute core (VGPR 68, proven)
//      + R9's verified float4 staging (one global load = 4 tile rows; kills
//      the ~95us of scalar-staging VALU that dominated R7)
//      + KC=2 -> 17.4 KB LDS -> ~2x R7 occupancy.
//      Lesson R8/R9: live set >128 regs => allocator spills regardless of
//      launch_bounds; 4x4 (live ~85) stays clear of the cliff.

#define NPATCH 4096
#define BT 64
#define KC 2
#define NPH 8

__global__ __launch_bounds__(256, 3) void adj_kernel(const float* __restrict__ x,
                                                     float* __restrict__ A) {
#pragma clang fp contract(off)
    // Row = 8 float4 chunks, chunk index c = kl*4+rc stored at c^((row>>2)&7),
    // elem = r&3. a-reads broadcast (free); b-reads 2-way (free); staging
    // writes 2-way (free); sq-phase reads 8-way but only ~6% of LDS traffic.
    __shared__ float4 Si[BT][8];
    __shared__ float4 Sj[BT][8];
    __shared__ float sqs[2][KC][BT];

    // linear -> lower-triangle (bi >= bj)
    int t = blockIdx.x;
    int bi = (int)((sqrtf(8.0f * (float)t + 1.0f) - 1.0f) * 0.5f);
    while ((bi + 1) * (bi + 2) / 2 <= t) ++bi;
    while (bi * (bi + 1) / 2 > t) --bi;
    int bj = t - bi * (bi + 1) / 2;

    const int i0 = bi * BT;
    const int j0 = bj * BT;
    const int tid = threadIdx.x;
    const int tx = tid & 15;       // j-cols tx*4..+3
    const int ty = tid >> 4;       // i-rows ty*4..+3

    float m[4][4];
#pragma unroll
    for (int u = 0; u < 4; ++u)
#pragma unroll
        for (int v = 0; v < 4; ++v) m[u][v] = -3.0e38f;

    for (int kp = 0; kp < NPH; ++kp) {
        __syncthreads();
        // ---- stage: 1024 float4 loads, 4/thread; load covers rows {16*dd+rl} ----
#pragma unroll
        for (int l = 0; l < 4; ++l) {
            int gid = l * 256 + tid;
            int side = gid >> 9;
            int q = gid & 511;             // kl(1) | r(4) | rl(4)
            int kl = q & 1;
            int r = (q >> 1) & 15;
            int rl = q >> 5;
            int k = kp * KC + kl;
            int b = side ? bj : bi;
            int h = rl * 64 + (r >> 2) * 16 + (b >> 2);
            int w0 = (r & 3) * 256 + k * 16 + ((4 * b) & 15);
            float4 v = *(const float4*)&x[h * 1024 + w0];
            const float* vp = (const float*)&v;
            int c = (kl << 2) | (r >> 2);
            int e = r & 3;
            float4* Sb = side ? &Sj[0][0] : &Si[0][0];
#pragma unroll
            for (int dd = 0; dd < 4; ++dd) {   // elem dd -> row 16*dd+rl
                int row = 16 * dd + rl;
                int ch = c ^ ((row >> 2) & 7);
                ((float*)&Sb[row * 8 + ch])[e] = vp[dd];
            }
        }
        __syncthreads();
        // ---- per-column sq: plain adds, r ascending (1 value/thread) ----
        {
            int side = tid >> 7;
            int kl = (tid >> 6) & 1;
            int row = tid & 63;
            const float4* Sb = side ? &Sj[row][0] : &Si[row][0];
            int swz = (row >> 2) & 7;
            float acc;
            {
                float4 v = Sb[(kl * 4) ^ swz];
                acc = v.x * v.x;
                float t1 = v.y * v.y; acc = acc + t1;
                float t2 = v.z * v.z; acc = acc + t2;
                float t3 = v.w * v.w; acc = acc + t3;
            }
#pragma unroll
            for (int rc = 1; rc < 4; ++rc) {
                float4 v = Sb[(kl * 4 + rc) ^ swz];
                float t0 = v.x * v.x; acc = acc + t0;
                float t1 = v.y * v.y; acc = acc + t1;
                float t2 = v.z * v.z; acc = acc + t2;
                float t3 = v.w * v.w; acc = acc + t3;
            }
            sqs[side][kl][row] = acc;
        }
        __syncthreads();
        // ---- compute: 4x4 cells, fmaf chains r ascending ----
#pragma unroll
        for (int kl = 0; kl < KC; ++kl) {
            float d[4][4];
#pragma unroll
            for (int u = 0; u < 4; ++u)
#pragma unroll
                for (int v = 0; v < 4; ++v) d[u][v] = 0.0f;
#pragma unroll
            for (int rc = 0; rc < 4; ++rc) {
                int c = kl * 4 + rc;
                float4 a[4], b[4];
#pragma unroll
                for (int u = 0; u < 4; ++u)
                    a[u] = Si[ty * 4 + u][c ^ (ty & 7)];   // (ty*4+u)>>2 == ty
#pragma unroll
                for (int v = 0; v < 4; ++v)
                    b[v] = Sj[tx * 4 + v][c ^ (tx & 7)];
#pragma unroll
                for (int u = 0; u < 4; ++u)
#pragma unroll
                    for (int v = 0; v < 4; ++v) {
                        d[u][v] = fmaf(a[u].x, b[v].x, d[u][v]);
                        d[u][v] = fmaf(a[u].y, b[v].y, d[u][v]);
                        d[u][v] = fmaf(a[u].z, b[v].z, d[u][v]);
                        d[u][v] = fmaf(a[u].w, b[v].w, d[u][v]);
                    }
            }
            float4 si4 = *(const float4*)&sqs[0][kl][ty * 4];
            float4 sj4 = *(const float4*)&sqs[1][kl][tx * 4];
            const float* sip = (const float*)&si4;
            const float* sjp = (const float*)&sj4;
#pragma unroll
            for (int u = 0; u < 4; ++u)
#pragma unroll
                for (int v = 0; v < 4; ++v) {
                    float s = sip[u] + sjp[v];            // fl(si+sj)
                    float d2 = fmaf(-2.0f, d[u][v], s);   // fl(s-2G)
                    m[u][v] = fmaxf(m[u][v], d2);
                }
        }
    }

    // ---- stores: direct + mirrored (A exactly symmetric) ----
#pragma unroll
    for (int u = 0; u < 4; ++u) {
        float4 o;
        o.x = (m[u][0] <= 49.0f) ? 1.0f : 0.0f;
        o.y = (m[u][1] <= 49.0f) ? 1.0f : 0.0f;
        o.z = (m[u][2] <= 49.0f) ? 1.0f : 0.0f;
        o.w = (m[u][3] <= 49.0f) ? 1.0f : 0.0f;
        *(float4*)&A[(size_t)(i0 + ty * 4 + u) * NPATCH + j0 + tx * 4] = o;
    }
    if (bi != bj) {
#pragma unroll
        for (int v = 0; v < 4; ++v) {
            float4 o;
            o.x = (m[0][v] <= 49.0f) ? 1.0f : 0.0f;
            o.y = (m[1][v] <= 49.0f) ? 1.0f : 0.0f;
            o.z = (m[2][v] <= 49.0f) ? 1.0f : 0.0f;
            o.w = (m[3][v] <= 49.0f) ? 1.0f : 0.0f;
            *(float4*)&A[(size_t)(j0 + tx * 4 + v) * NPATCH + i0 + ty * 4] = o;
        }
    }
}

extern "C" void kernel_launch(void* const* d_in, const int* in_sizes, int n_in,
                              void* d_out, int out_size, void* d_ws, size_t ws_size,
                              hipStream_t stream) {
    const float* x = (const float*)d_in[0];
    float* A = (float*)d_out;
    (void)d_ws; (void)ws_size;

    const int nblk = (NPATCH / BT) * (NPATCH / BT + 1) / 2;  // 2080
    adj_kernel<<<nblk, 256, 0, stream>>>(x, A);
}